// Round 1
// 15.345 us; speedup vs baseline: 1.8818x; 1.8818x over previous
//
#include <hip/hip_runtime.h>
#include <math.h>

// Quanvolution hybrid classifier, fully fused, per-thread statevector.
// Wire w <-> state-index bit (3-w): wire0 mask=8, wire1=4, wire2=2, wire3=1.
// Gates are applied directly to the 16 complex amplitudes held in registers.

#define G_RX(MASK, C, S) do { \
  _Pragma("unroll") \
  for (int r = 0; r < 16; ++r) { \
    if ((r & (MASK)) == 0) { const int r1 = r | (MASK); \
      float ar = ur[r], ai = ui[r], br = ur[r1], bi = ui[r1]; \
      ur[r]  = (C)*ar + (S)*bi;  ui[r]  = (C)*ai - (S)*br; \
      ur[r1] = (C)*br + (S)*ai;  ui[r1] = (C)*bi - (S)*ar; } } } while (0)

#define G_RY(MASK, C, S) do { \
  _Pragma("unroll") \
  for (int r = 0; r < 16; ++r) { \
    if ((r & (MASK)) == 0) { const int r1 = r | (MASK); \
      float ar = ur[r], ai = ui[r], br = ur[r1], bi = ui[r1]; \
      ur[r]  = (C)*ar - (S)*br;  ui[r]  = (C)*ai - (S)*bi; \
      ur[r1] = (S)*ar + (C)*br;  ui[r1] = (S)*ai + (C)*bi; } } } while (0)

#define G_CRX(MC, MT, C, S) do { \
  _Pragma("unroll") \
  for (int r = 0; r < 16; ++r) { \
    if ((r & (MC)) != 0 && (r & (MT)) == 0) { const int r1 = r | (MT); \
      float ar = ur[r], ai = ui[r], br = ur[r1], bi = ui[r1]; \
      ur[r]  = (C)*ar + (S)*bi;  ui[r]  = (C)*ai - (S)*br; \
      ur[r1] = (C)*br + (S)*ai;  ui[r1] = (C)*bi - (S)*ar; } } } while (0)

__global__ __launch_bounds__(256) void quanv_fused_kernel(
    const float* __restrict__ xin,   // (B, 784)
    const float* __restrict__ theta, // (8,)
    const float* __restrict__ Wm,    // (10, 784)
    const float* __restrict__ bv,    // (10,)
    float* __restrict__ out,         // (B, 10) log-softmax
    int B)
{
    __shared__ __align__(16) float gq[16];  // [0..7]=cos(theta/2), [8..15]=sin(theta/2)
    __shared__ float red[4][10];

    const int b = blockIdx.x;
    const int t = threadIdx.x;

    // gate constants: 8 sincos once per block, broadcast via 64B of LDS
    if (t < 8) {
        float sv, cv;
        sincosf(theta[t] * 0.5f, &sv, &cv);
        gq[t] = cv; gq[8 + t] = sv;
    }
    __syncthreads();

    float acc[10];
#pragma unroll
    for (int c = 0; c < 10; ++c) acc[c] = 0.f;

    if (t < 196) {
        const int pi = t / 14, pj = t % 14;
        const float* prow = xin + (size_t)b * 784 + pi * 56 + pj * 2;
        const float2 rA = *(const float2*)prow;        // x[r,c], x[r,c+1]
        const float2 rB = *(const float2*)(prow + 28); // x[r+1,c], x[r+1,c+1]

        float s0, c0, s1, c1, s2, c2, s3, c3;
        sincosf(rA.x * 0.5f, &s0, &c0);
        sincosf(rA.y * 0.5f, &s1, &c1);
        sincosf(rB.x * 0.5f, &s2, &c2);
        sincosf(rB.y * 0.5f, &s3, &c3);

        const float4 gcl = *(const float4*)&gq[0];   // cos th0..3
        const float4 gch = *(const float4*)&gq[4];   // cos th4..7
        const float4 gsl = *(const float4*)&gq[8];   // sin th0..3
        const float4 gsh = *(const float4*)&gq[12];  // sin th4..7

        // Fold gates 0..2 (rx@w0, ry@w1, rz@w3 -- disjoint wires) into the
        // per-wire encoding 2-vectors (exact).
        // v0' = rx(th0)[c0,s0] (complex)
        const float v0r0 = gcl.x * c0, v0i0 = -gsl.x * s0;
        const float v0r1 = gcl.x * s0, v0i1 = -gsl.x * c0;
        // v1' = ry(th1)[c1,s1] (real)
        const float v10 = gcl.y * c1 - gsl.y * s1;
        const float v11 = gsl.y * c1 + gcl.y * s1;
        // v2  = [c2,s2] (real)
        // v3' = rz(th2)[c3,s3] (complex)
        const float v3r0 = gcl.z * c3, v3i0 = -gsl.z * c3;
        const float v3r1 = gcl.z * s3, v3i1 =  gsl.z * s3;

        float p01r[4], p01i[4], p23r[4], p23i[4];
        p01r[0] = v0r0 * v10; p01i[0] = v0i0 * v10;
        p01r[1] = v0r0 * v11; p01i[1] = v0i0 * v11;
        p01r[2] = v0r1 * v10; p01i[2] = v0i1 * v10;
        p01r[3] = v0r1 * v11; p01i[3] = v0i1 * v11;
        p23r[0] = c2 * v3r0;  p23i[0] = c2 * v3i0;
        p23r[1] = c2 * v3r1;  p23i[1] = c2 * v3i1;
        p23r[2] = s2 * v3r0;  p23i[2] = s2 * v3i0;
        p23r[3] = s2 * v3r1;  p23i[3] = s2 * v3i1;

        float ur[16], ui[16];
#pragma unroll
        for (int i = 0; i < 16; ++i) {
            const float ar = p01r[i >> 2], ai = p01i[i >> 2];
            const float br = p23r[i & 3],  bi = p23i[i & 3];
            ur[i] = ar * br - ai * bi;
            ui[i] = ar * bi + ai * br;
        }

        // remaining gates, applied in-register
        G_CRX(8, 2, gcl.w, gsl.w);   // crx(th3) ctrl w0 -> w2
        G_RY (1,    gch.x, gsh.x);   // ry (th4) w3
        G_RX (2,    gch.y, gsh.y);   // rx (th5) w2
        G_CRX(4, 1, gch.z, gsh.z);   // crx(th6) ctrl w1 -> w3
        // rz(th7)@w0 is diagonal (pure phase): no effect on |psi|^2 -> dropped

        // PauliZ expectations
        float m0 = 0.f, m1 = 0.f, m2 = 0.f, m3 = 0.f;
#pragma unroll
        for (int k = 0; k < 16; ++k) {
            const float p = fmaf(ur[k], ur[k], ui[k] * ui[k]);
            m0 += (k & 8) ? -p : p;
            m1 += (k & 4) ? -p : p;
            m2 += (k & 2) ? -p : p;
            m3 += (k & 1) ? -p : p;
        }

        // this patch's features live at columns 4t..4t+3 of W: one float4 per class
        const float4* wp = (const float4*)Wm + t;   // row stride = 784/4 = 196
#pragma unroll
        for (int c = 0; c < 10; ++c) {
            const float4 w = wp[c * 196];
            acc[c] = fmaf(m3, w.w, fmaf(m2, w.z, fmaf(m1, w.y, m0 * w.x)));
        }
    }

    // block-wide reduction of the 10 partial logits
#pragma unroll
    for (int c = 0; c < 10; ++c) {
        float v = acc[c];
        v += __shfl_down(v, 32, 64);
        v += __shfl_down(v, 16, 64);
        v += __shfl_down(v, 8, 64);
        v += __shfl_down(v, 4, 64);
        v += __shfl_down(v, 2, 64);
        v += __shfl_down(v, 1, 64);
        acc[c] = v;
    }
    const int wave = t >> 6;
    if ((t & 63) == 0) {
#pragma unroll
        for (int c = 0; c < 10; ++c) red[wave][c] = acc[c];
    }
    __syncthreads();

    // log-softmax over 10 classes (thread 0)
    if (t == 0) {
        float l[10];
        float mx = -1e30f;
#pragma unroll
        for (int c = 0; c < 10; ++c) {
            l[c] = red[0][c] + red[1][c] + red[2][c] + red[3][c] + bv[c];
            mx = fmaxf(mx, l[c]);
        }
        float sum = 0.f;
#pragma unroll
        for (int c = 0; c < 10; ++c) sum += expf(l[c] - mx);
        const float ls = logf(sum);
        float* o = out + (size_t)b * 10;
#pragma unroll
        for (int c = 0; c < 10; ++c) o[c] = l[c] - mx - ls;
    }
}

extern "C" void kernel_launch(void* const* d_in, const int* in_sizes, int n_in,
                              void* d_out, int out_size, void* d_ws, size_t ws_size,
                              hipStream_t stream) {
    const float* x     = (const float*)d_in[0];
    const float* theta = (const float*)d_in[1];
    const float* W     = (const float*)d_in[2];
    const float* bias  = (const float*)d_in[3];
    float* out         = (float*)d_out;

    const int B = in_sizes[0] / 784;
    quanv_fused_kernel<<<B, 256, 0, stream>>>(x, theta, W, bias, out, B);
}

// Round 2
// 14.170 us; speedup vs baseline: 2.0379x; 1.0829x over previous
//
#include <hip/hip_runtime.h>
#include <math.h>

// Quanvolution hybrid classifier — closed-form feature map.
//
// After folding rx(th0)@0, ry(th1)@1, rz(th2)@3 into the RY encoding, the
// remaining gates {crx(th3,0->2), ry(th4)@3, rx(th5)@2, crx(th6,1->3)} act on
// disjoint wire pairs {0,2} and {1,3}, so the state factorizes and each
// PauliZ expectation has a closed form in the full patch angles:
//   m0 = cos(th0) * cos(a0)
//   m1 = cos(a1 + th1)
//   m2 = cos(a2) * (A + B*cos(a0))
//   m3 = (C1 + C2*m1)*(K1*cos(a3) + K2*sin(a3)) + C5*(1-m1)*sin(a3)
// with A=(cos th5+cos(th3+th5))/2, B=cos th0*(cos th5-cos(th3+th5))/2,
//      C1=(1+cos th6)/2, C2=(1-cos th6)/2, K1=cos th4, K2=-sin th4*cos th2,
//      C5=sin th6*sin th2/2.  rz(th7)@0 is a pure phase on measurement basis.

__global__ __launch_bounds__(256) void quanv_fused_kernel(
    const float* __restrict__ xin,   // (B, 784)
    const float* __restrict__ theta, // (8,)
    const float* __restrict__ Wm,    // (10, 784)
    const float* __restrict__ bv,    // (10,)
    float* __restrict__ out,         // (B, 10) log-softmax
    int B)
{
    __shared__ float kc[9];          // broadcast constants derived from theta
    __shared__ float red[4][10];

    const int b = blockIdx.x;
    const int t = threadIdx.x;

    if (t == 0) {
        const float t0 = theta[0], t1 = theta[1], t2 = theta[2], t3 = theta[3];
        const float t4 = theta[4], t5 = theta[5], t6 = theta[6];
        const float c5g = cosf(t5), c35 = cosf(t3 + t5);
        const float c6 = cosf(t6), s6 = sinf(t6);
        kc[0] = cosf(t0);                       // k0
        kc[1] = t1;                             // th1 (additive shift)
        kc[2] = 0.5f * (c5g + c35);             // A
        kc[3] = 0.5f * cosf(t0) * (c5g - c35);  // B
        kc[4] = 0.5f * (1.f + c6);              // C1
        kc[5] = 0.5f * (1.f - c6);              // C2
        kc[6] = cosf(t4);                       // K1
        kc[7] = -sinf(t4) * cosf(t2);           // K2
        kc[8] = 0.5f * s6 * sinf(t2);           // C5
    }
    __syncthreads();

    float acc[10];
#pragma unroll
    for (int c = 0; c < 10; ++c) acc[c] = 0.f;

    if (t < 196) {
        const int pi = t / 14, pj = t % 14;
        const float* prow = xin + (size_t)b * 784 + pi * 56 + pj * 2;
        const float2 rA = *(const float2*)prow;        // a0, a1
        const float2 rB = *(const float2*)(prow + 28); // a2, a3

        const float k0 = kc[0], th1 = kc[1], A = kc[2], Bc = kc[3];
        const float C1 = kc[4], C2 = kc[5], K1 = kc[6], K2 = kc[7], C5 = kc[8];

        const float ca0 = __cosf(rA.x);
        const float u   = __cosf(rA.y + th1);          // m1
        const float ca2 = __cosf(rB.x);
        float sa3, ca3;
        __sincosf(rB.y, &sa3, &ca3);

        const float m0 = k0 * ca0;
        const float m1 = u;
        const float m2 = ca2 * fmaf(Bc, ca0, A);
        const float zu = fmaf(K1, ca3, K2 * sa3);
        const float m3 = fmaf(fmaf(C2, u, C1), zu, C5 * sa3 * (1.f - u));

        // this patch's features hit columns 4t..4t+3 of W: one float4 per class
        const float4* wp = (const float4*)Wm + t;      // row stride = 196 float4
#pragma unroll
        for (int c = 0; c < 10; ++c) {
            const float4 w = wp[c * 196];
            acc[c] = fmaf(m3, w.w, fmaf(m2, w.z, fmaf(m1, w.y, m0 * w.x)));
        }
    }

    // block-wide reduction of the 10 partial logits
#pragma unroll
    for (int c = 0; c < 10; ++c) {
        float v = acc[c];
        v += __shfl_down(v, 32, 64);
        v += __shfl_down(v, 16, 64);
        v += __shfl_down(v, 8, 64);
        v += __shfl_down(v, 4, 64);
        v += __shfl_down(v, 2, 64);
        v += __shfl_down(v, 1, 64);
        acc[c] = v;
    }
    const int wave = t >> 6;
    if ((t & 63) == 0) {
#pragma unroll
        for (int c = 0; c < 10; ++c) red[wave][c] = acc[c];
    }
    __syncthreads();

    // log-softmax over 10 classes (thread 0)
    if (t == 0) {
        float l[10];
        float mx = -1e30f;
#pragma unroll
        for (int c = 0; c < 10; ++c) {
            l[c] = red[0][c] + red[1][c] + red[2][c] + red[3][c] + bv[c];
            mx = fmaxf(mx, l[c]);
        }
        float sum = 0.f;
#pragma unroll
        for (int c = 0; c < 10; ++c) sum += expf(l[c] - mx);
        const float ls = logf(sum);
        float* o = out + (size_t)b * 10;
#pragma unroll
        for (int c = 0; c < 10; ++c) o[c] = l[c] - mx - ls;
    }
}

extern "C" void kernel_launch(void* const* d_in, const int* in_sizes, int n_in,
                              void* d_out, int out_size, void* d_ws, size_t ws_size,
                              hipStream_t stream) {
    const float* x     = (const float*)d_in[0];
    const float* theta = (const float*)d_in[1];
    const float* W     = (const float*)d_in[2];
    const float* bias  = (const float*)d_in[3];
    float* out         = (float*)d_out;

    const int B = in_sizes[0] / 784;
    quanv_fused_kernel<<<B, 256, 0, stream>>>(x, theta, W, bias, out, B);
}

// Round 3
// 12.897 us; speedup vs baseline: 2.2390x; 1.0987x over previous
//
#include <hip/hip_runtime.h>
#include <math.h>

// Quanvolution hybrid classifier — closed-form feature map, 4 images/block.
//
// Closed forms (derived by folding rx(th0)@0, ry(th1)@1, rz(th2)@3 into the
// RY encoding; remaining gates act on disjoint wire pairs {0,2},{1,3}):
//   m0 = cos(th0) * cos(a0)
//   m1 = cos(a1 + th1)
//   m2 = cos(a2) * (A + B*cos(a0))
//   m3 = (C1 + C2*m1)*(K1*cos(a3) + K2*sin(a3)) + C5*(1-m1)*sin(a3)
// A=(cos th5+cos(th3+th5))/2, B=cos th0*(cos th5-cos(th3+th5))/2,
// C1=(1+cos th6)/2, C2=(1-cos th6)/2, K1=cos th4, K2=-sin th4*cos th2,
// C5=sin th6*sin th2/2.  rz(th7)@0 is a pure phase.
//
// Block layout: 256 threads, 4 images.
//   Phase A: threads 0..195 -> features of 4 images into LDS (float4 each).
//   Phase B: wave w does image w's GEMV + butterfly-reduce + softmax.

__global__ __launch_bounds__(256) void quanv_fused_kernel(
    const float* __restrict__ xin,   // (B, 784)
    const float* __restrict__ theta, // (8,)
    const float* __restrict__ Wm,    // (10, 784)
    const float* __restrict__ bv,    // (10,)
    float* __restrict__ out,         // (B, 10) log-softmax
    int B)
{
    __shared__ float kc[9];
    __shared__ __align__(16) float4 feats[4][196];   // 12.5 KB

    const int t  = threadIdx.x;
    const int b0 = blockIdx.x * 4;

    if (t == 0) {
        const float t0 = theta[0], t1 = theta[1], t2 = theta[2], t3 = theta[3];
        const float t4 = theta[4], t5 = theta[5], t6 = theta[6];
        const float c5g = cosf(t5), c35 = cosf(t3 + t5);
        const float c6 = cosf(t6), s6 = sinf(t6);
        kc[0] = cosf(t0);
        kc[1] = t1;
        kc[2] = 0.5f * (c5g + c35);
        kc[3] = 0.5f * cosf(t0) * (c5g - c35);
        kc[4] = 0.5f * (1.f + c6);
        kc[5] = 0.5f * (1.f - c6);
        kc[6] = cosf(t4);
        kc[7] = -sinf(t4) * cosf(t2);
        kc[8] = 0.5f * s6 * sinf(t2);
    }
    __syncthreads();

    // ---- Phase A: per-patch features for 4 images ----
    if (t < 196) {
        const int pi = t / 14, pj = t % 14;
        const float* base = xin + (size_t)b0 * 784 + pi * 56 + pj * 2;

        // issue all 8 loads up front (8-deep memory-level parallelism)
        float2 rA[4], rB[4];
#pragma unroll
        for (int i = 0; i < 4; ++i) {
            rA[i] = *(const float2*)(base + i * 784);
            rB[i] = *(const float2*)(base + i * 784 + 28);
        }

        const float k0 = kc[0], th1 = kc[1], A = kc[2], Bc = kc[3];
        const float C1 = kc[4], C2 = kc[5], K1 = kc[6], K2 = kc[7], C5 = kc[8];

#pragma unroll
        for (int i = 0; i < 4; ++i) {
            const float ca0 = __cosf(rA[i].x);
            const float u   = __cosf(rA[i].y + th1);       // m1
            const float ca2 = __cosf(rB[i].x);
            float sa3, ca3;
            __sincosf(rB[i].y, &sa3, &ca3);

            const float m0 = k0 * ca0;
            const float m2 = ca2 * fmaf(Bc, ca0, A);
            const float zu = fmaf(K1, ca3, K2 * sa3);
            const float m3 = fmaf(fmaf(C2, u, C1), zu, C5 * sa3 * (1.f - u));

            feats[i][t] = make_float4(m0, u, m2, m3);
        }
    }
    __syncthreads();

    // ---- Phase B: wave w handles image w ----
    const int w = t >> 6, l = t & 63;

    float acc[10];
#pragma unroll
    for (int c = 0; c < 10; ++c) acc[c] = 0.f;

    const float4* fw = feats[w];
    const float4* W4 = (const float4*)Wm;   // [10][196] float4

#pragma unroll
    for (int k = 0; k < 3; ++k) {
        const int p = l + 64 * k;
        const float4 f = fw[p];
#pragma unroll
        for (int c = 0; c < 10; ++c) {
            const float4 wv = W4[c * 196 + p];
            acc[c] = fmaf(f.w, wv.w, fmaf(f.z, wv.z,
                     fmaf(f.y, wv.y, fmaf(f.x, wv.x, acc[c]))));
        }
    }
    if (l < 4) {                      // tail: patches 192..195
        const int p = 192 + l;
        const float4 f = fw[p];
#pragma unroll
        for (int c = 0; c < 10; ++c) {
            const float4 wv = W4[c * 196 + p];
            acc[c] = fmaf(f.w, wv.w, fmaf(f.z, wv.z,
                     fmaf(f.y, wv.y, fmaf(f.x, wv.x, acc[c]))));
        }
    }

    // butterfly: after 6 steps every lane holds the full sum per class
    float logit[10];
#pragma unroll
    for (int c = 0; c < 10; ++c) {
        float v = acc[c];
        v += __shfl_xor(v, 32, 64);
        v += __shfl_xor(v, 16, 64);
        v += __shfl_xor(v, 8, 64);
        v += __shfl_xor(v, 4, 64);
        v += __shfl_xor(v, 2, 64);
        v += __shfl_xor(v, 1, 64);
        logit[c] = v + bv[c];
    }

    // log-softmax, redundantly on all lanes of the wave; lane 0 stores
    float mx = -1e30f;
#pragma unroll
    for (int c = 0; c < 10; ++c) mx = fmaxf(mx, logit[c]);
    float sum = 0.f;
#pragma unroll
    for (int c = 0; c < 10; ++c) sum += expf(logit[c] - mx);
    const float ls = logf(sum);

    const int img = b0 + w;
    if (l == 0 && img < B) {
        float* o = out + (size_t)img * 10;
#pragma unroll
        for (int c = 0; c < 10; ++c) o[c] = logit[c] - mx - ls;
    }
}

extern "C" void kernel_launch(void* const* d_in, const int* in_sizes, int n_in,
                              void* d_out, int out_size, void* d_ws, size_t ws_size,
                              hipStream_t stream) {
    const float* x     = (const float*)d_in[0];
    const float* theta = (const float*)d_in[1];
    const float* W     = (const float*)d_in[2];
    const float* bias  = (const float*)d_in[3];
    float* out         = (float*)d_out;

    const int B = in_sizes[0] / 784;
    const int grid = (B + 3) / 4;
    quanv_fused_kernel<<<grid, 256, 0, stream>>>(x, theta, W, bias, out, B);
}

// Round 4
// 10.707 us; speedup vs baseline: 2.6970x; 1.2045x over previous
//
#include <hip/hip_runtime.h>
#include <math.h>

// Quanvolution hybrid classifier — closed-form feature map, wave-autonomous.
//
// Closed forms (fold rx(th0)@0, ry(th1)@1, rz(th2)@3 into the RY encoding;
// remaining gates act on disjoint wire pairs {0,2},{1,3}):
//   m0 = cos(th0) * cos(a0)
//   m1 = cos(a1 + th1)
//   m2 = cos(a2) * (A + B*cos(a0))
//   m3 = (C1 + C2*m1)*(K1*cos(a3) + K2*sin(a3)) + C5*(1-m1)*sin(a3)
// A=(cos th5+cos(th3+th5))/2, B=cos th0*(cos th5-cos(th3+th5))/2,
// C1=(1+cos th6)/2, C2=(1-cos th6)/2, K1=cos th4, K2=-sin th4*cos th2,
// C5=sin th6*sin th2/2.  rz(th7)@0 is a pure phase.
//
// Structure: one WAVE per image, no __syncthreads, no LDS. Lane l owns
// patches {l, l+64, l+128} (+{192+l} for l<4): computes their features in
// registers and dots them against the matching float4 columns of W, then a
// 6-step butterfly gives every lane the 10 logits; softmax is wave-redundant.

__global__ __launch_bounds__(256) void quanv_fused_kernel(
    const float* __restrict__ xin,   // (B, 784)
    const float* __restrict__ theta, // (8,)
    const float* __restrict__ Wm,    // (10, 784)
    const float* __restrict__ bv,    // (10,)
    float* __restrict__ out,         // (B, 10) log-softmax
    int B)
{
    const int t = threadIdx.x;
    const int w = t >> 6, l = t & 63;
    const int img = blockIdx.x * 4 + w;
    if (img >= B) return;            // wave-uniform; legal: kernel has no barriers

    const float* ib = xin + (size_t)img * 784;
    const bool tail = (l < 4);

    // ---- issue all x loads first (hide HBM latency under kc trig) ----
    float2 rA[4], rB[4];
#pragma unroll
    for (int k = 0; k < 3; ++k) {
        const int p = l + 64 * k;
        const int pi = p / 14, pj = p % 14;
        const float* pr = ib + pi * 56 + pj * 2;
        rA[k] = *(const float2*)pr;
        rB[k] = *(const float2*)(pr + 28);
    }
    {
        const int p = tail ? (192 + l) : l;   // dummy for non-tail lanes
        const int pi = p / 14, pj = p % 14;
        const float* pr = ib + pi * 56 + pj * 2;
        rA[3] = *(const float2*)pr;
        rB[3] = *(const float2*)(pr + 28);
    }

    // ---- theta-derived constants, redundantly per lane (overlaps latency) ----
    const float t0 = theta[0], th1 = theta[1], t2 = theta[2], t3 = theta[3];
    const float t4 = theta[4], t5 = theta[5], t6 = theta[6];
    const float c5g = cosf(t5), c35 = cosf(t3 + t5);
    const float c6 = cosf(t6), s6 = sinf(t6);
    const float k0 = cosf(t0);
    const float A  = 0.5f * (c5g + c35);
    const float Bc = 0.5f * k0 * (c5g - c35);
    const float C1 = 0.5f * (1.f + c6);
    const float C2 = 0.5f * (1.f - c6);
    const float K1 = cosf(t4);
    const float K2 = -sinf(t4) * cosf(t2);
    const float C5 = 0.5f * s6 * sinf(t2);

    auto featf = [&](float2 a, float2 b) -> float4 {
        const float ca0 = __cosf(a.x);
        const float u   = __cosf(a.y + th1);            // m1
        const float ca2 = __cosf(b.x);
        float sa3, ca3;
        __sincosf(b.y, &sa3, &ca3);
        const float m0 = k0 * ca0;
        const float m2 = ca2 * fmaf(Bc, ca0, A);
        const float zu = fmaf(K1, ca3, K2 * sa3);
        const float m3 = fmaf(fmaf(C2, u, C1), zu, C5 * sa3 * (1.f - u));
        return make_float4(m0, u, m2, m3);
    };

    // ---- GEMV against this lane's own patches ----
    float acc[10];
#pragma unroll
    for (int c = 0; c < 10; ++c) acc[c] = 0.f;

    const float4* W4 = (const float4*)Wm;   // [10][196] float4
#pragma unroll
    for (int k = 0; k < 3; ++k) {
        const float4 f = featf(rA[k], rB[k]);
        const int p = l + 64 * k;
#pragma unroll
        for (int c = 0; c < 10; ++c) {
            const float4 wv = W4[c * 196 + p];
            acc[c] = fmaf(f.w, wv.w, fmaf(f.z, wv.z,
                     fmaf(f.y, wv.y, fmaf(f.x, wv.x, acc[c]))));
        }
    }
    if (tail) {
        const float4 f = featf(rA[3], rB[3]);
        const int p = 192 + l;
#pragma unroll
        for (int c = 0; c < 10; ++c) {
            const float4 wv = W4[c * 196 + p];
            acc[c] = fmaf(f.w, wv.w, fmaf(f.z, wv.z,
                     fmaf(f.y, wv.y, fmaf(f.x, wv.x, acc[c]))));
        }
    }

    // ---- butterfly: every lane ends with all 10 logits ----
    float logit[10];
#pragma unroll
    for (int c = 0; c < 10; ++c) {
        float v = acc[c];
        v += __shfl_xor(v, 32, 64);
        v += __shfl_xor(v, 16, 64);
        v += __shfl_xor(v, 8, 64);
        v += __shfl_xor(v, 4, 64);
        v += __shfl_xor(v, 2, 64);
        v += __shfl_xor(v, 1, 64);
        logit[c] = v + bv[c];
    }

    // ---- log-softmax, wave-redundant; lanes 0..9 store coalesced ----
    float mx = -1e30f;
#pragma unroll
    for (int c = 0; c < 10; ++c) mx = fmaxf(mx, logit[c]);
    float sum = 0.f;
#pragma unroll
    for (int c = 0; c < 10; ++c) sum += __expf(logit[c] - mx);
    const float ls = __logf(sum);

    if (l < 10) {
        float v = logit[9];
#pragma unroll
        for (int c = 8; c >= 0; --c) v = (l == c) ? logit[c] : v;
        out[(size_t)img * 10 + l] = v - mx - ls;
    }
}

extern "C" void kernel_launch(void* const* d_in, const int* in_sizes, int n_in,
                              void* d_out, int out_size, void* d_ws, size_t ws_size,
                              hipStream_t stream) {
    const float* x     = (const float*)d_in[0];
    const float* theta = (const float*)d_in[1];
    const float* W     = (const float*)d_in[2];
    const float* bias  = (const float*)d_in[3];
    float* out         = (float*)d_out;

    const int B = in_sizes[0] / 784;
    const int grid = (B + 3) / 4;
    quanv_fused_kernel<<<grid, 256, 0, stream>>>(x, theta, W, bias, out, B);
}

// Round 5
// 10.250 us; speedup vs baseline: 2.8172x; 1.0446x over previous
//
#include <hip/hip_runtime.h>
#include <math.h>

// Quanvolution hybrid classifier — closed-form feature map, wave-autonomous,
// DPP (VALU-pipe) wave reduction. No LDS, no barriers, no DS-pipe traffic.
//
// Closed forms (fold rx(th0)@0, ry(th1)@1, rz(th2)@3 into the RY encoding;
// remaining gates act on disjoint wire pairs {0,2},{1,3}):
//   m0 = cos(th0) * cos(a0)
//   m1 = cos(a1 + th1)
//   m2 = cos(a2) * (A + B*cos(a0))
//   m3 = (C1 + C2*m1)*(K1*cos(a3) + K2*sin(a3)) + C5*(1-m1)*sin(a3)
// A=(cos th5+cos(th3+th5))/2, B=cos th0*(cos th5-cos(th3+th5))/2,
// C1=(1+cos th6)/2, C2=(1-cos th6)/2, K1=cos th4, K2=-sin th4*cos th2,
// C5=sin th6*sin th2/2.  rz(th7)@0 is a pure phase.

// wave64 sum-reduction entirely on the VALU pipe via DPP; returns the total
// (taken from lane 63) as a wave-uniform value.
__device__ __forceinline__ float wave_sum_dpp(float v) {
#define DPP_ADD(CTRL, RMASK)                                                  \
    v += __int_as_float(__builtin_amdgcn_update_dpp(                          \
        0, __float_as_int(v), (CTRL), (RMASK), 0xf, true))
    DPP_ADD(0x111, 0xf);   // row_shr:1
    DPP_ADD(0x112, 0xf);   // row_shr:2
    DPP_ADD(0x114, 0xf);   // row_shr:4
    DPP_ADD(0x118, 0xf);   // row_shr:8  -> lanes 15/31/47/63 hold row sums
    DPP_ADD(0x142, 0xa);   // row_bcast:15 -> rows 1,3 accumulate rows 0,2
    DPP_ADD(0x143, 0xc);   // row_bcast:31 -> lane 63 holds the wave total
#undef DPP_ADD
    return __int_as_float(__builtin_amdgcn_readlane(__float_as_int(v), 63));
}

__global__ __launch_bounds__(256) void quanv_fused_kernel(
    const float* __restrict__ xin,   // (B, 784)
    const float* __restrict__ theta, // (8,)
    const float* __restrict__ Wm,    // (10, 784)
    const float* __restrict__ bv,    // (10,)
    float* __restrict__ out,         // (B, 10) log-softmax
    int B)
{
    const int t = threadIdx.x;
    const int w = t >> 6, l = t & 63;
    const int img = blockIdx.x * 4 + w;
    if (img >= B) return;            // wave-uniform; legal: no barriers anywhere

    const float* ib = xin + (size_t)img * 784;
    const bool tail = (l < 4);

    // ---- issue x loads first (hide HBM/L2 latency under kc trig) ----
    float2 rA[4], rB[4];
#pragma unroll
    for (int k = 0; k < 3; ++k) {
        const int p = l + 64 * k;
        const int pi = p / 14, pj = p % 14;
        const float* pr = ib + pi * 56 + pj * 2;
        rA[k] = *(const float2*)pr;
        rB[k] = *(const float2*)(pr + 28);
    }
    if (tail) {
        const int p = 192 + l;
        const int pi = p / 14, pj = p % 14;
        const float* pr = ib + pi * 56 + pj * 2;
        rA[3] = *(const float2*)pr;
        rB[3] = *(const float2*)(pr + 28);
    }

    // ---- theta-derived constants, per lane, hardware trig (args ~N(0,1)) ----
    const float t0 = theta[0], th1 = theta[1], t2 = theta[2], t3 = theta[3];
    const float t4 = theta[4], t5 = theta[5], t6 = theta[6];
    const float c5g = __cosf(t5), c35 = __cosf(t3 + t5);
    const float c6 = __cosf(t6), s6 = __sinf(t6);
    const float k0 = __cosf(t0);
    const float A  = 0.5f * (c5g + c35);
    const float Bc = 0.5f * k0 * (c5g - c35);
    const float C1 = 0.5f * (1.f + c6);
    const float C2 = 0.5f * (1.f - c6);
    const float K1 = __cosf(t4);
    const float K2 = -__sinf(t4) * __cosf(t2);
    const float C5 = 0.5f * s6 * __sinf(t2);

    auto featf = [&](float2 a, float2 b) -> float4 {
        const float ca0 = __cosf(a.x);
        const float u   = __cosf(a.y + th1);            // m1
        const float ca2 = __cosf(b.x);
        float sa3, ca3;
        __sincosf(b.y, &sa3, &ca3);
        const float m0 = k0 * ca0;
        const float m2 = ca2 * fmaf(Bc, ca0, A);
        const float zu = fmaf(K1, ca3, K2 * sa3);
        const float m3 = fmaf(fmaf(C2, u, C1), zu, C5 * sa3 * (1.f - u));
        return make_float4(m0, u, m2, m3);
    };

    // ---- GEMV against this lane's own patches ----
    float acc[10];
#pragma unroll
    for (int c = 0; c < 10; ++c) acc[c] = 0.f;

    const float4* W4 = (const float4*)Wm;   // [10][196] float4
#pragma unroll
    for (int k = 0; k < 3; ++k) {
        const float4 f = featf(rA[k], rB[k]);
        const int p = l + 64 * k;
#pragma unroll
        for (int c = 0; c < 10; ++c) {
            const float4 wv = W4[c * 196 + p];
            acc[c] = fmaf(f.w, wv.w, fmaf(f.z, wv.z,
                     fmaf(f.y, wv.y, fmaf(f.x, wv.x, acc[c]))));
        }
    }
    if (tail) {
        const float4 f = featf(rA[3], rB[3]);
        const int p = 192 + l;
#pragma unroll
        for (int c = 0; c < 10; ++c) {
            const float4 wv = W4[c * 196 + p];
            acc[c] = fmaf(f.w, wv.w, fmaf(f.z, wv.z,
                     fmaf(f.y, wv.y, fmaf(f.x, wv.x, acc[c]))));
        }
    }

    // ---- wave reduction on the VALU pipe; logits become wave-uniform ----
    float logit[10];
#pragma unroll
    for (int c = 0; c < 10; ++c) logit[c] = wave_sum_dpp(acc[c]) + bv[c];

    // ---- log-softmax on uniform values ----
    float mx = -1e30f;
#pragma unroll
    for (int c = 0; c < 10; ++c) mx = fmaxf(mx, logit[c]);
    float sum = 0.f;
#pragma unroll
    for (int c = 0; c < 10; ++c) sum += __expf(logit[c] - mx);
    const float ls = __logf(sum);

    // ---- lanes 0..9 store the 10 log-probs (coalesced 40B) ----
    if (l < 10) {
        float v = logit[9];
#pragma unroll
        for (int c = 8; c >= 0; --c) v = (l == c) ? logit[c] : v;
        out[(size_t)img * 10 + l] = v - mx - ls;
    }
}

extern "C" void kernel_launch(void* const* d_in, const int* in_sizes, int n_in,
                              void* d_out, int out_size, void* d_ws, size_t ws_size,
                              hipStream_t stream) {
    const float* x     = (const float*)d_in[0];
    const float* theta = (const float*)d_in[1];
    const float* W     = (const float*)d_in[2];
    const float* bias  = (const float*)d_in[3];
    float* out         = (float*)d_out;

    const int B = in_sizes[0] / 784;
    const int grid = (B + 3) / 4;
    quanv_fused_kernel<<<grid, 256, 0, stream>>>(x, theta, W, bias, out, B);
}